// Round 5
// baseline (1400.748 us; speedup 1.0000x reference)
//
#include <hip/hip_runtime.h>
#include <cstdint>
#include <cstddef>

// Problem constants
#define BT     32768   // batch (titles)
#define NW     30      // words per title
#define VOCAB  32000
#define WD     300     // word dim
#define CH     400     // conv channels
#define AD     200     // attention dim

// Padded bf16 layouts
#define EMB_LD   320   // emb_bf16 [VOCAB][320]  (300 + pad)
#define E3_LD    640   // E3 bf16 [VOCAB+1][640] (600 + pad); row ZROW = zeros
#define ZROW     32000
#define U_LD     928   // U bf16 [BT][928]       (900 + pad)
#define WCT_ROWS 512   // WcT bf16 [512][928]    (400 + pad rows)
#define EXPA_LD  32    // expa [BT][32]          (30 + pad)

typedef __attribute__((ext_vector_type(8))) short bf16x8;
typedef __attribute__((ext_vector_type(4))) float f32x4;

__device__ __forceinline__ float blo(unsigned int u) {
  union { unsigned int i; float f; } x; x.i = u << 16; return x.f;
}
__device__ __forceinline__ float bhi(unsigned int u) {
  union { unsigned int i; float f; } x; x.i = u & 0xffff0000u; return x.f;
}
__device__ __forceinline__ unsigned short f2bf(float f) {
  union { float f; unsigned int i; } x; x.f = f;
  unsigned int r = x.i + 0x7FFFu + ((x.i >> 16) & 1u);   // RNE
  return (unsigned short)(r >> 16);
}
__device__ __forceinline__ unsigned int pack2bf(float a, float b) {
  return (unsigned int)f2bf(a) | ((unsigned int)f2bf(b) << 16);
}

// Fast tanh via native v_exp_f32: tanh(x) = 1 - 2/(exp(2x)+1). Saturates correctly.
__device__ __forceinline__ float tanh_fast(float x) {
  float e = __expf(2.0f * x);
  return 1.0f - __fdividef(2.0f, e + 1.0f);
}

// ---------------------------------------------------------------------------
// Prep: Mt[i][k*200+d] = sum_c conv_w[c,i,k]*v[c,d]  (fp32, [300][600])
//       bias2[d]       = sum_c conv_b[c]*v[c,d] + vb[d]
// ---------------------------------------------------------------------------
__global__ void prep_Mt_bias(const float* __restrict__ conv_w,
                             const float* __restrict__ conv_b,
                             const float* __restrict__ v,
                             const float* __restrict__ vb,
                             float* __restrict__ Mt,
                             float* __restrict__ bias2) {
  int blk = blockIdx.x;      // 0..899 -> Mt, 900 -> bias2
  int d = threadIdx.x;       // 0..199
  if (blk < 900) {
    int i = blk / 3, k = blk % 3;
    float acc = 0.f;
    #pragma unroll 4
    for (int c = 0; c < CH; ++c)
      acc += conv_w[(c * WD + i) * 3 + k] * v[c * AD + d];
    Mt[i * 600 + k * AD + d] = acc;
  } else {
    float acc = vb[d];
    #pragma unroll 4
    for (int c = 0; c < CH; ++c)
      acc += conv_b[c] * v[c * AD + d];
    bias2[d] = acc;
  }
}

// MtT[n][i] = bf16(Mt[i][n]) for n<600,i<300 else 0.  [E3_LD][EMB_LD]
__global__ void conv_MtT(const float* __restrict__ Mt, unsigned short* __restrict__ MtT) {
  int n = blockIdx.x;    // 640
  int i = threadIdx.x;   // 320
  float val = (n < 600 && i < WD) ? Mt[i * 600 + n] : 0.f;
  MtT[n * EMB_LD + i] = f2bf(val);
}

// WcT[c][kk] = bf16(conv_w[c, i, k]), kk = k*300+i; zero-padded. [512][928]
__global__ void prep_WcT(const float* __restrict__ conv_w, unsigned short* __restrict__ WcT) {
  int c = blockIdx.x;    // 512
  for (int kk = threadIdx.x; kk < U_LD; kk += 256) {
    float val = 0.f;
    if (c < CH && kk < 900) {
      int k = kk / WD, i = kk - k * WD;
      val = conv_w[(c * WD + i) * 3 + k];
    }
    WcT[(size_t)c * U_LD + kk] = f2bf(val);
  }
}

// emb -> bf16, zero-padded cols. [VOCAB][320]
__global__ void prep_emb_bf16(const float* __restrict__ emb, unsigned short* __restrict__ embb) {
  int idx = blockIdx.x * 256 + threadIdx.x;
  if (idx >= VOCAB * EMB_LD) return;
  int r = idx / EMB_LD, c = idx - r * EMB_LD;
  embb[idx] = (c < WD) ? f2bf(emb[(size_t)r * WD + c]) : (unsigned short)0;
}

// Zero the sentinel row of E3 (used for out-of-range conv taps)
__global__ void zero_zrow(unsigned short* __restrict__ row) {
  int i = blockIdx.x * 256 + threadIdx.x;
  if (i < E3_LD) row[i] = 0;
}

// ---------------------------------------------------------------------------
// bf16 MFMA GEMM: C[M,N] = A[M,K] @ Bt[N,K]^T. 128x128 tile, K-step 32.
// OUT_BF16: store bf16, optional e3bias added to cols [200,400).
// else: fp32 store with col<N guard + rank-1 bias_m[r]*bias_n[c].
// ---------------------------------------------------------------------------
template<bool OUT_BF16>
__global__ __launch_bounds__(256) void gemm_mfma(
    const unsigned short* __restrict__ A, int lda,
    const unsigned short* __restrict__ Bt, int ldb,
    void* __restrict__ Cp, int ldc, int N, int K,
    const float* __restrict__ bias_m, const float* __restrict__ bias_n,
    const float* __restrict__ e3bias) {
  __shared__ unsigned short As[128][40];   // +8 pad
  __shared__ unsigned short Bs[128][40];
  int tid = threadIdx.x;
  int lane = tid & 63, wave = tid >> 6;
  int row0 = blockIdx.y * 128, col0 = blockIdx.x * 128;
  int wm = (wave & 1) * 64, wn = (wave >> 1) * 64;
  int lr = lane & 15, quad = lane >> 4;

  f32x4 acc[4][4];
  #pragma unroll
  for (int i = 0; i < 4; ++i)
    #pragma unroll
    for (int j = 0; j < 4; ++j) acc[i][j] = (f32x4){0.f, 0.f, 0.f, 0.f};

  int r0 = tid >> 2, ko0 = (tid & 3) * 8;
  int r1 = (tid + 256) >> 2, ko1 = ((tid + 256) & 3) * 8;

  for (int k0 = 0; k0 < K; k0 += 32) {
    float4 av0 = *(const float4*)(A + (size_t)(row0 + r0) * lda + k0 + ko0);
    float4 av1 = *(const float4*)(A + (size_t)(row0 + r1) * lda + k0 + ko1);
    float4 bv0 = *(const float4*)(Bt + (size_t)(col0 + r0) * ldb + k0 + ko0);
    float4 bv1 = *(const float4*)(Bt + (size_t)(col0 + r1) * ldb + k0 + ko1);
    __syncthreads();
    *(float4*)&As[r0][ko0] = av0;
    *(float4*)&As[r1][ko1] = av1;
    *(float4*)&Bs[r0][ko0] = bv0;
    *(float4*)&Bs[r1][ko1] = bv1;
    __syncthreads();

    bf16x8 af[4], bfr[4];
    #pragma unroll
    for (int mi = 0; mi < 4; ++mi)
      af[mi] = *(const bf16x8*)&As[wm + mi * 16 + lr][quad * 8];
    #pragma unroll
    for (int ni = 0; ni < 4; ++ni)
      bfr[ni] = *(const bf16x8*)&Bs[wn + ni * 16 + lr][quad * 8];
    #pragma unroll
    for (int mi = 0; mi < 4; ++mi)
      #pragma unroll
      for (int ni = 0; ni < 4; ++ni)
        acc[mi][ni] = __builtin_amdgcn_mfma_f32_16x16x32_bf16(
            af[mi], bfr[ni], acc[mi][ni], 0, 0, 0);
  }

  // Epilogue. C/D layout: col = lane&15, row = quad*4 + reg.
  if (OUT_BF16) {
    unsigned short* C = (unsigned short*)Cp;
    #pragma unroll
    for (int mi = 0; mi < 4; ++mi)
      #pragma unroll
      for (int ni = 0; ni < 4; ++ni) {
        int c = col0 + wn + ni * 16 + lr;
        float cb = (e3bias && c >= 200 && c < 400) ? e3bias[c - 200] : 0.f;
        #pragma unroll
        for (int reg = 0; reg < 4; ++reg) {
          int r = row0 + wm + mi * 16 + quad * 4 + reg;
          C[(size_t)r * ldc + c] = f2bf(acc[mi][ni][reg] + cb);
        }
      }
  } else {
    float* C = (float*)Cp;
    #pragma unroll
    for (int mi = 0; mi < 4; ++mi)
      #pragma unroll
      for (int ni = 0; ni < 4; ++ni) {
        int c = col0 + wn + ni * 16 + lr;
        if (c < N) {
          float bn = bias_n[c];
          #pragma unroll
          for (int reg = 0; reg < 4; ++reg) {
            int r = row0 + wm + mi * 16 + quad * 4 + reg;
            C[(size_t)r * ldc + c] = acc[mi][ni][reg] + bias_m[r] * bn;
          }
        }
      }
  }
}

// ---------------------------------------------------------------------------
// Scores, title-per-wave: lane = (n, half). Each lane sums 96/104 d-elements
// of tanh(E3[t_{n-1},d] + E3[t_n,200+d] + E3[t_{n+1},400+d])*q[d].
// Edge taps use the zeroed ZROW. Output: expa[b*32+n] = exp(score).
// NOTE: all __shfl calls are wave-uniform (no divergence) with clamped
// source lanes; edge patching happens AFTER via scalar selects. A divergent
// shfl here (R4) read from exec-masked-off source lanes -> garbage.
// ---------------------------------------------------------------------------
__global__ __launch_bounds__(256) void scores_kernel(
    const int* __restrict__ tok, const unsigned short* __restrict__ E3,
    const float* __restrict__ q, float* __restrict__ expa) {
  __shared__ float qs[AD];
  int tid = threadIdx.x;
  if (tid < AD) qs[tid] = q[tid];
  __syncthreads();
  int wave = tid >> 6, lane = tid & 63;
  int b = blockIdx.x * 4 + wave;
  int n = lane >> 1, half = lane & 1;
  int tk = (lane < NW) ? tok[b * NW + lane] : 0;
  int nc0 = (n >= 1) ? n - 1 : 0;            // clamped source lanes
  int nc2 = (n < NW - 1) ? n + 1 : NW - 1;
  int t1 = __shfl(tk, n, 64);
  int t0 = __shfl(tk, nc0, 64);
  int t2 = __shfl(tk, nc2, 64);
  if (n == 0) t0 = ZROW;
  if (n >= NW - 1) t2 = ZROW;
  if (n >= NW) { t0 = ZROW; t1 = ZROW; }     // lanes 60-63 idle-safe
  const unsigned short* p0 = E3 + (unsigned)(t0 * E3_LD);
  const unsigned short* p1 = E3 + (unsigned)(t1 * E3_LD) + 200;
  const unsigned short* p2 = E3 + (unsigned)(t2 * E3_LD) + 400;
  int d = half * 96;            // half0: d 0..95 (12 chunks), half1: 96..199 (13)
  int nch = 12 + half;
  uint4 A0 = *(const uint4*)(p0 + d);
  uint4 A1 = *(const uint4*)(p1 + d);
  uint4 A2 = *(const uint4*)(p2 + d);
  float acc = 0.f;
  for (int c = 0; c < nch; ++c) {
    int dn = d + 8;             // over-prefetch on last iter stays in-row (<=607<640)
    uint4 B0 = *(const uint4*)(p0 + dn);
    uint4 B1 = *(const uint4*)(p1 + dn);
    uint4 B2 = *(const uint4*)(p2 + dn);
    float4 qa = *(const float4*)&qs[d];
    float4 qb = *(const float4*)&qs[d + 4];
    acc = fmaf(tanh_fast(blo(A0.x) + blo(A1.x) + blo(A2.x)), qa.x, acc);
    acc = fmaf(tanh_fast(bhi(A0.x) + bhi(A1.x) + bhi(A2.x)), qa.y, acc);
    acc = fmaf(tanh_fast(blo(A0.y) + blo(A1.y) + blo(A2.y)), qa.z, acc);
    acc = fmaf(tanh_fast(bhi(A0.y) + bhi(A1.y) + bhi(A2.y)), qa.w, acc);
    acc = fmaf(tanh_fast(blo(A0.z) + blo(A1.z) + blo(A2.z)), qb.x, acc);
    acc = fmaf(tanh_fast(bhi(A0.z) + bhi(A1.z) + bhi(A2.z)), qb.y, acc);
    acc = fmaf(tanh_fast(blo(A0.w) + blo(A1.w) + blo(A2.w)), qb.z, acc);
    acc = fmaf(tanh_fast(bhi(A0.w) + bhi(A1.w) + bhi(A2.w)), qb.w, acc);
    A0 = B0; A1 = B1; A2 = B2;
    d = dn;
  }
  acc += __shfl_xor(acc, 1, 64);
  // |score| <= sum|q| ~ 16 -> exp safe in fp32; softmax needs no max-shift.
  if (half == 0 && n < NW) expa[b * EXPA_LD + n] = __expf(acc);
}

// ---------------------------------------------------------------------------
// Softmax-over-batch denominators, stage 1: 128 blocks x 256 titles each.
// part[n][blk] = sum over block's titles of expa[b][n].
// ---------------------------------------------------------------------------
__global__ __launch_bounds__(256) void softmax_part(const float* __restrict__ expa,
                                                    float* __restrict__ part) {
  __shared__ float P[256][33];
  int tid = threadIdx.x;
  const float* row = expa + (size_t)(blockIdx.x * 256 + tid) * EXPA_LD;
  #pragma unroll
  for (int j = 0; j < 7; ++j) {
    float4 vv = *(const float4*)(row + j * 4);
    P[tid][j * 4] = vv.x; P[tid][j * 4 + 1] = vv.y;
    P[tid][j * 4 + 2] = vv.z; P[tid][j * 4 + 3] = vv.w;
  }
  P[tid][28] = row[28]; P[tid][29] = row[29];
  __syncthreads();
  int wave = tid >> 6, lane = tid & 63;
  for (int n = wave * 8; n < wave * 8 + 8 && n < NW; ++n) {
    float s = P[lane * 4][n] + P[lane * 4 + 1][n] + P[lane * 4 + 2][n] + P[lane * 4 + 3][n];
    #pragma unroll
    for (int off = 32; off > 0; off >>= 1) s += __shfl_down(s, off, 64);
    if (lane == 0) part[n * 128 + blockIdx.x] = s;
  }
}

// Stage 2: rinv[n] = 1 / sum_blk part[n][blk]
__global__ void softmax_fin(const float* __restrict__ part, float* __restrict__ rinv) {
  int n = blockIdx.x;          // 30
  int lane = threadIdx.x;      // 64
  float s = part[n * 128 + lane] + part[n * 128 + 64 + lane];
  #pragma unroll
  for (int off = 32; off > 0; off >>= 1) s += __shfl_down(s, off, 64);
  if (lane == 0) rinv[n] = 1.0f / s;
}

// ---------------------------------------------------------------------------
// U[b, k*300+i] = sum_m alpha[b, m-k+1] * emb[tok[b,m], i]  -> bf16, stride 928
// Salpha[b] = sum_n alpha[b,n].  alpha = expa * rinv.
// ---------------------------------------------------------------------------
__global__ __launch_bounds__(192) void build_U(
    const int* __restrict__ tok, const unsigned short* __restrict__ embb,
    const float* __restrict__ expa, const float* __restrict__ rinv,
    unsigned short* __restrict__ U, float* __restrict__ Salpha) {
  int b = blockIdx.x;
  int tid = threadIdx.x;
  __shared__ float alpha[NW];
  __shared__ int ltok[NW];
  if (tid < NW) {
    ltok[tid] = tok[b * NW + tid];
    alpha[tid] = expa[(size_t)b * EXPA_LD + tid] * rinv[tid];
  }
  __syncthreads();
  if (tid == 0) {
    float s = 0.f;
    #pragma unroll
    for (int n = 0; n < NW; ++n) s += alpha[n];
    Salpha[b] = s;
  }
  unsigned short* Ub = U + (size_t)b * U_LD;
  if (tid < 150) {
    float a0 = 0.f, a1 = 0.f, a2 = 0.f;   // col x = 2*tid
    float b0 = 0.f, b1 = 0.f, b2 = 0.f;   // col y = 2*tid+1
    #pragma unroll 2
    for (int m = 0; m < NW; ++m) {
      int t = ltok[m];
      float w0 = (m + 1 < NW) ? alpha[m + 1] : 0.f;
      float w1 = alpha[m];
      float w2 = (m >= 1) ? alpha[m - 1] : 0.f;
      unsigned int u = *(const unsigned int*)(embb + (size_t)t * EMB_LD + 2 * tid);
      float x = blo(u), y = bhi(u);
      a0 = fmaf(w0, x, a0); b0 = fmaf(w0, y, b0);
      a1 = fmaf(w1, x, a1); b1 = fmaf(w1, y, b1);
      a2 = fmaf(w2, x, a2); b2 = fmaf(w2, y, b2);
    }
    *(unsigned int*)(Ub + 2 * tid)       = pack2bf(a0, b0);
    *(unsigned int*)(Ub + 300 + 2 * tid) = pack2bf(a1, b1);
    *(unsigned int*)(Ub + 600 + 2 * tid) = pack2bf(a2, b2);
  } else if (tid < 164) {
    *(unsigned int*)(Ub + 900 + 2 * (tid - 150)) = 0u;   // zero pad 900..927
  }
}

// ---------------------------------------------------------------------------
extern "C" void kernel_launch(void* const* d_in, const int* in_sizes, int n_in,
                              void* d_out, int out_size, void* d_ws, size_t ws_size,
                              hipStream_t stream) {
  const int*   tok    = (const int*)d_in[0];
  const float* emb    = (const float*)d_in[1];
  const float* conv_w = (const float*)d_in[2];
  const float* conv_b = (const float*)d_in[3];
  const float* v      = (const float*)d_in[4];
  const float* vb     = (const float*)d_in[5];
  const float* q      = (const float*)d_in[6];
  float* out = (float*)d_out;

  // Workspace layout (byte offsets). Total ~87.8 MB.
  char* wb = (char*)d_ws;
  float* bias2           = (float*)(wb + 0);          // 200 f32
  float* rinv            = (float*)(wb + 4096);       // 30 f32
  float* part            = (float*)(wb + 8192);       // 30*128 f32 -> 23552
  float* Salpha          = (float*)(wb + 24576);      // 32768 f32 -> 155648
  float* expa            = (float*)(wb + 155648);     // 32768*32 f32 -> 4349952
  float* Mt              = (float*)(wb + 4349952);    // 180000 f32 -> 5069952
  unsigned short* embb   = (unsigned short*)(wb + 5070848);   // 20.48MB -> 25550848
  unsigned short* MtT    = (unsigned short*)(wb + 25550848);  // 409600 -> 25960448
  unsigned short* WcT    = (unsigned short*)(wb + 25960448);  // 950272 -> 26910720
  unsigned short* big    = (unsigned short*)(wb + 26910720);  // E3 (41MB) / U (60.8MB)
  unsigned short* E3 = big;
  unsigned short* U  = big;   // E3 dead after scores_kernel

  // 1. Prep
  hipLaunchKernelGGL(prep_Mt_bias, dim3(901), dim3(200), 0, stream,
                     conv_w, conv_b, v, vb, Mt, bias2);
  hipLaunchKernelGGL(conv_MtT, dim3(E3_LD), dim3(EMB_LD), 0, stream, Mt, MtT);
  hipLaunchKernelGGL(prep_WcT, dim3(WCT_ROWS), dim3(256), 0, stream, conv_w, WcT);
  hipLaunchKernelGGL(prep_emb_bf16, dim3((VOCAB * EMB_LD) / 256), dim3(256), 0, stream,
                     emb, embb);
  hipLaunchKernelGGL(zero_zrow, dim3(3), dim3(256), 0, stream, E3 + (size_t)ZROW * E3_LD);
  // 2. E3[32000,640]bf16 = embb @ MtT^T, bias2 folded into cols [200,400)
  hipLaunchKernelGGL((gemm_mfma<true>), dim3(E3_LD / 128, VOCAB / 128), dim3(256), 0, stream,
                     embb, EMB_LD, MtT, EMB_LD, (void*)E3, E3_LD, E3_LD, EMB_LD,
                     (const float*)nullptr, (const float*)nullptr, bias2);
  // 3. exp(scores) -> expa[b][n]
  hipLaunchKernelGGL(scores_kernel, dim3(BT / 4), dim3(256), 0, stream,
                     tok, E3, q, expa);
  // 4. Softmax denominators (2-stage, deterministic)
  hipLaunchKernelGGL(softmax_part, dim3(128), dim3(256), 0, stream, expa, part);
  hipLaunchKernelGGL(softmax_fin, dim3(NW), dim3(64), 0, stream, part, rinv);
  // 5. U[32768,928]bf16 + Salpha
  hipLaunchKernelGGL(build_U, dim3(BT), dim3(192), 0, stream,
                     tok, embb, expa, rinv, U, Salpha);
  // 6. out[32768,400]f32 = U @ WcT^T + Salpha ⊗ conv_b
  hipLaunchKernelGGL((gemm_mfma<false>), dim3(WCT_ROWS / 128, BT / 128), dim3(256), 0, stream,
                     U, U_LD, WcT, U_LD, (void*)out, CH, CH, U_LD,
                     Salpha, conv_b, (const float*)nullptr);
}

// Round 6
// 507.594 us; speedup vs baseline: 2.7596x; 2.7596x over previous
//
#include <hip/hip_runtime.h>
#include <cstdint>
#include <cstddef>

// Problem constants
#define BT     32768   // batch (titles)
#define NW     30      // words per title
#define VOCAB  32000
#define WD     300     // word dim
#define CH     400     // conv channels
#define AD     200     // attention dim

// Padded bf16 layouts
#define EMB_LD   320   // emb_bf16 [VOCAB][320]  (300 + pad)
#define E3_LD    640   // E3 bf16 [VOCAB+1][640] (600 + pad); row ZROW = zeros
#define ZROW     32000
#define U_LD     928   // U bf16 [BT][928]       (900 + pad)
#define WCT_ROWS 512   // WcT bf16 [512][928]    (400 + pad rows)
#define EXPA_LD  32    // expa [BT][32]          (30 + pad)

typedef __attribute__((ext_vector_type(8))) short bf16x8;
typedef __attribute__((ext_vector_type(4))) float f32x4;

__device__ __forceinline__ float blo(unsigned int u) {
  union { unsigned int i; float f; } x; x.i = u << 16; return x.f;
}
__device__ __forceinline__ float bhi(unsigned int u) {
  union { unsigned int i; float f; } x; x.i = u & 0xffff0000u; return x.f;
}
__device__ __forceinline__ unsigned short f2bf(float f) {
  union { float f; unsigned int i; } x; x.f = f;
  unsigned int r = x.i + 0x7FFFu + ((x.i >> 16) & 1u);   // RNE
  return (unsigned short)(r >> 16);
}
__device__ __forceinline__ unsigned int pack2bf(float a, float b) {
  return (unsigned int)f2bf(a) | ((unsigned int)f2bf(b) << 16);
}

// ---------------------------------------------------------------------------
// Prep: Mt[i][k*200+d] = 2 * sum_c conv_w[c,i,k]*v[c,d]   (NOTE the 2x:
// E3 then holds 2s, so scores can use q*tanh(s) = q - 2q/(exp(2s)+1)
// without a per-element doubling. 2x in bf16 is exact.)
//       bias2[d] = 2 * (sum_c conv_b[c]*v[c,d] + vb[d])
//       q2s[d] = -2*q[d];  qsum[0] = sum_d q[d]
// ---------------------------------------------------------------------------
__global__ void prep_Mt_bias(const float* __restrict__ conv_w,
                             const float* __restrict__ conv_b,
                             const float* __restrict__ v,
                             const float* __restrict__ vb,
                             const float* __restrict__ q,
                             float* __restrict__ Mt,
                             float* __restrict__ bias2,
                             float* __restrict__ q2s,
                             float* __restrict__ qsum) {
  int blk = blockIdx.x;      // 0..899 -> Mt, 900 -> bias2, 901 -> q2s/qsum
  int d = threadIdx.x;       // 0..199
  if (blk < 900) {
    int i = blk / 3, k = blk % 3;
    float acc = 0.f;
    #pragma unroll 4
    for (int c = 0; c < CH; ++c)
      acc += conv_w[(c * WD + i) * 3 + k] * v[c * AD + d];
    Mt[i * 600 + k * AD + d] = 2.0f * acc;
  } else if (blk == 900) {
    float acc = vb[d];
    #pragma unroll 4
    for (int c = 0; c < CH; ++c)
      acc += conv_b[c] * v[c * AD + d];
    bias2[d] = 2.0f * acc;
  } else {
    q2s[d] = -2.0f * q[d];
    if (d == 0) {
      float s = 0.f;
      for (int i = 0; i < AD; ++i) s += q[i];
      qsum[0] = s;
    }
  }
}

// MtT[n][i] = bf16(Mt[i][n]) for n<600,i<300 else 0.  [E3_LD][EMB_LD]
__global__ void conv_MtT(const float* __restrict__ Mt, unsigned short* __restrict__ MtT) {
  int n = blockIdx.x;    // 640
  int i = threadIdx.x;   // 320
  float val = (n < 600 && i < WD) ? Mt[i * 600 + n] : 0.f;
  MtT[n * EMB_LD + i] = f2bf(val);
}

// WcT[c][kk] = bf16(conv_w[c, i, k]), kk = k*300+i; zero-padded. [512][928]
__global__ void prep_WcT(const float* __restrict__ conv_w, unsigned short* __restrict__ WcT) {
  int c = blockIdx.x;    // 512
  for (int kk = threadIdx.x; kk < U_LD; kk += 256) {
    float val = 0.f;
    if (c < CH && kk < 900) {
      int k = kk / WD, i = kk - k * WD;
      val = conv_w[(c * WD + i) * 3 + k];
    }
    WcT[(size_t)c * U_LD + kk] = f2bf(val);
  }
}

// emb -> bf16, zero-padded cols. [VOCAB][320]
__global__ void prep_emb_bf16(const float* __restrict__ emb, unsigned short* __restrict__ embb) {
  int idx = blockIdx.x * 256 + threadIdx.x;
  if (idx >= VOCAB * EMB_LD) return;
  int r = idx / EMB_LD, c = idx - r * EMB_LD;
  embb[idx] = (c < WD) ? f2bf(emb[(size_t)r * WD + c]) : (unsigned short)0;
}

// Zero the sentinel row of E3 (used for out-of-range conv taps)
__global__ void zero_zrow(unsigned short* __restrict__ row) {
  int i = blockIdx.x * 256 + threadIdx.x;
  if (i < E3_LD) row[i] = 0;
}

// ---------------------------------------------------------------------------
// bf16 MFMA GEMM: C[M,N] = A[M,K] @ Bt[N,K]^T. 128x128 tile, K-step 32.
// OUT_BF16: store bf16, optional e3bias added to cols [200,400).
// else: fp32 store with col<N guard + rank-1 bias_m[r]*bias_n[c].
// ---------------------------------------------------------------------------
template<bool OUT_BF16>
__global__ __launch_bounds__(256) void gemm_mfma(
    const unsigned short* __restrict__ A, int lda,
    const unsigned short* __restrict__ Bt, int ldb,
    void* __restrict__ Cp, int ldc, int N, int K,
    const float* __restrict__ bias_m, const float* __restrict__ bias_n,
    const float* __restrict__ e3bias) {
  __shared__ unsigned short As[128][40];   // +8 pad
  __shared__ unsigned short Bs[128][40];
  int tid = threadIdx.x;
  int lane = tid & 63, wave = tid >> 6;
  int row0 = blockIdx.y * 128, col0 = blockIdx.x * 128;
  int wm = (wave & 1) * 64, wn = (wave >> 1) * 64;
  int lr = lane & 15, quad = lane >> 4;

  f32x4 acc[4][4];
  #pragma unroll
  for (int i = 0; i < 4; ++i)
    #pragma unroll
    for (int j = 0; j < 4; ++j) acc[i][j] = (f32x4){0.f, 0.f, 0.f, 0.f};

  int r0 = tid >> 2, ko0 = (tid & 3) * 8;
  int r1 = (tid + 256) >> 2, ko1 = ((tid + 256) & 3) * 8;

  for (int k0 = 0; k0 < K; k0 += 32) {
    float4 av0 = *(const float4*)(A + (size_t)(row0 + r0) * lda + k0 + ko0);
    float4 av1 = *(const float4*)(A + (size_t)(row0 + r1) * lda + k0 + ko1);
    float4 bv0 = *(const float4*)(Bt + (size_t)(col0 + r0) * ldb + k0 + ko0);
    float4 bv1 = *(const float4*)(Bt + (size_t)(col0 + r1) * ldb + k0 + ko1);
    __syncthreads();
    *(float4*)&As[r0][ko0] = av0;
    *(float4*)&As[r1][ko1] = av1;
    *(float4*)&Bs[r0][ko0] = bv0;
    *(float4*)&Bs[r1][ko1] = bv1;
    __syncthreads();

    bf16x8 af[4], bfr[4];
    #pragma unroll
    for (int mi = 0; mi < 4; ++mi)
      af[mi] = *(const bf16x8*)&As[wm + mi * 16 + lr][quad * 8];
    #pragma unroll
    for (int ni = 0; ni < 4; ++ni)
      bfr[ni] = *(const bf16x8*)&Bs[wn + ni * 16 + lr][quad * 8];
    #pragma unroll
    for (int mi = 0; mi < 4; ++mi)
      #pragma unroll
      for (int ni = 0; ni < 4; ++ni)
        acc[mi][ni] = __builtin_amdgcn_mfma_f32_16x16x32_bf16(
            af[mi], bfr[ni], acc[mi][ni], 0, 0, 0);
  }

  // Epilogue. C/D layout: col = lane&15, row = quad*4 + reg.
  if (OUT_BF16) {
    unsigned short* C = (unsigned short*)Cp;
    #pragma unroll
    for (int mi = 0; mi < 4; ++mi)
      #pragma unroll
      for (int ni = 0; ni < 4; ++ni) {
        int c = col0 + wn + ni * 16 + lr;
        float cb = (e3bias && c >= 200 && c < 400) ? e3bias[c - 200] : 0.f;
        #pragma unroll
        for (int reg = 0; reg < 4; ++reg) {
          int r = row0 + wm + mi * 16 + quad * 4 + reg;
          C[(size_t)r * ldc + c] = f2bf(acc[mi][ni][reg] + cb);
        }
      }
  } else {
    float* C = (float*)Cp;
    #pragma unroll
    for (int mi = 0; mi < 4; ++mi)
      #pragma unroll
      for (int ni = 0; ni < 4; ++ni) {
        int c = col0 + wn + ni * 16 + lr;
        if (c < N) {
          float bn = bias_n[c];
          #pragma unroll
          for (int reg = 0; reg < 4; ++reg) {
            int r = row0 + wm + mi * 16 + quad * 4 + reg;
            C[(size_t)r * ldc + c] = acc[mi][ni][reg] + bias_m[r] * bn;
          }
        }
      }
  }
}

// ---------------------------------------------------------------------------
// Scores, TITLE-per-wave (R3's coalesced memory shape, amortized overhead):
// wave = one title; unrolled loop over n; lanes 0..49 spread over d (4 each).
// E3 holds 2s (Mt pre-doubled); q*tanh(s) = q - 2q/(exp(2s)+1), so
// score = Qsum + sum_d q2[d]/(exp(2s_d)+1) with q2 = -2q.
// Per-n results parked in lane n via cndmask; ONE exp + ONE coalesced store
// at the end. All __shfl source lanes uniform (loop unrolled) -> readlane.
// ---------------------------------------------------------------------------
__global__ __launch_bounds__(256) void scores_kernel(
    const int* __restrict__ tok, const unsigned short* __restrict__ E3,
    const float* __restrict__ q2s, const float* __restrict__ qsum,
    float* __restrict__ expa) {
  __shared__ float qs[AD];
  int tid = threadIdx.x;
  if (tid < AD) qs[tid] = q2s[tid];
  __syncthreads();
  int wave = tid >> 6, lane = tid & 63;
  int b = blockIdx.x * 4 + wave;
  int tk = tok[b * NW + ((lane < NW) ? lane : 0)];
  int d0 = (lane < 50) ? lane * 4 : 0;
  float4 qv = make_float4(0.f, 0.f, 0.f, 0.f);
  if (lane < 50) qv = *(const float4*)&qs[d0];   // lanes >=50 contribute 0
  float Qsum = qsum[0];
  float myscore = 0.f;

  #pragma unroll
  for (int n = 0; n < NW; ++n) {
    int t1 = __shfl(tk, n, 64);
    int t0 = (n == 0) ? ZROW : __shfl(tk, n - 1, 64);
    int t2 = (n == NW - 1) ? ZROW : __shfl(tk, n + 1, 64);
    uint2 u0 = *(const uint2*)(E3 + (size_t)(unsigned)t0 * E3_LD + d0);
    uint2 u1 = *(const uint2*)(E3 + (size_t)(unsigned)t1 * E3_LD + 200 + d0);
    uint2 u2 = *(const uint2*)(E3 + (size_t)(unsigned)t2 * E3_LD + 400 + d0);
    float s0 = blo(u0.x) + blo(u1.x) + blo(u2.x);
    float s1 = bhi(u0.x) + bhi(u1.x) + bhi(u2.x);
    float s2 = blo(u0.y) + blo(u1.y) + blo(u2.y);
    float s3 = bhi(u0.y) + bhi(u1.y) + bhi(u2.y);
    float acc;
    acc = qv.x * __builtin_amdgcn_rcpf(__expf(s0) + 1.0f);
    acc = fmaf(qv.y, __builtin_amdgcn_rcpf(__expf(s1) + 1.0f), acc);
    acc = fmaf(qv.z, __builtin_amdgcn_rcpf(__expf(s2) + 1.0f), acc);
    acc = fmaf(qv.w, __builtin_amdgcn_rcpf(__expf(s3) + 1.0f), acc);
    #pragma unroll
    for (int off = 1; off < 64; off <<= 1) acc += __shfl_xor(acc, off, 64);
    myscore = (lane == n) ? acc : myscore;
  }
  // |score| <= sum|q| ~ 16 -> exp safe in fp32; softmax needs no max-shift.
  float e = __expf(Qsum + myscore);
  if (lane < NW) expa[(size_t)b * EXPA_LD + lane] = e;
}

// ---------------------------------------------------------------------------
// Softmax-over-batch denominators, stage 1: 128 blocks x 256 titles each.
// part[n][blk] = sum over block's titles of expa[b][n].
// ---------------------------------------------------------------------------
__global__ __launch_bounds__(256) void softmax_part(const float* __restrict__ expa,
                                                    float* __restrict__ part) {
  __shared__ float P[256][33];
  int tid = threadIdx.x;
  const float* row = expa + (size_t)(blockIdx.x * 256 + tid) * EXPA_LD;
  #pragma unroll
  for (int j = 0; j < 7; ++j) {
    float4 vv = *(const float4*)(row + j * 4);
    P[tid][j * 4] = vv.x; P[tid][j * 4 + 1] = vv.y;
    P[tid][j * 4 + 2] = vv.z; P[tid][j * 4 + 3] = vv.w;
  }
  P[tid][28] = row[28]; P[tid][29] = row[29];
  __syncthreads();
  int wave = tid >> 6, lane = tid & 63;
  for (int n = wave * 8; n < wave * 8 + 8 && n < NW; ++n) {
    float s = P[lane * 4][n] + P[lane * 4 + 1][n] + P[lane * 4 + 2][n] + P[lane * 4 + 3][n];
    #pragma unroll
    for (int off = 32; off > 0; off >>= 1) s += __shfl_down(s, off, 64);
    if (lane == 0) part[n * 128 + blockIdx.x] = s;
  }
}

// Stage 2: rinv[n] = 1 / sum_blk part[n][blk]
__global__ void softmax_fin(const float* __restrict__ part, float* __restrict__ rinv) {
  int n = blockIdx.x;          // 30
  int lane = threadIdx.x;      // 64
  float s = part[n * 128 + lane] + part[n * 128 + 64 + lane];
  #pragma unroll
  for (int off = 32; off > 0; off >>= 1) s += __shfl_down(s, off, 64);
  if (lane == 0) rinv[n] = 1.0f / s;
}

// ---------------------------------------------------------------------------
// U[b, k*300+i] = sum_m alpha[b, m-k+1] * emb[tok[b,m], i]  -> bf16, stride 928
// Salpha[b] = sum_n alpha[b,n].  alpha = expa * rinv.
// ---------------------------------------------------------------------------
__global__ __launch_bounds__(192) void build_U(
    const int* __restrict__ tok, const unsigned short* __restrict__ embb,
    const float* __restrict__ expa, const float* __restrict__ rinv,
    unsigned short* __restrict__ U, float* __restrict__ Salpha) {
  int b = blockIdx.x;
  int tid = threadIdx.x;
  __shared__ float alpha[NW];
  __shared__ int ltok[NW];
  if (tid < NW) {
    ltok[tid] = tok[b * NW + tid];
    alpha[tid] = expa[(size_t)b * EXPA_LD + tid] * rinv[tid];
  }
  __syncthreads();
  if (tid == 0) {
    float s = 0.f;
    #pragma unroll
    for (int n = 0; n < NW; ++n) s += alpha[n];
    Salpha[b] = s;
  }
  unsigned short* Ub = U + (size_t)b * U_LD;
  if (tid < 150) {
    float a0 = 0.f, a1 = 0.f, a2 = 0.f;   // col x = 2*tid
    float b0 = 0.f, b1 = 0.f, b2 = 0.f;   // col y = 2*tid+1
    #pragma unroll 2
    for (int m = 0; m < NW; ++m) {
      int t = ltok[m];
      float w0 = (m + 1 < NW) ? alpha[m + 1] : 0.f;
      float w1 = alpha[m];
      float w2 = (m >= 1) ? alpha[m - 1] : 0.f;
      unsigned int u = *(const unsigned int*)(embb + (size_t)t * EMB_LD + 2 * tid);
      float x = blo(u), y = bhi(u);
      a0 = fmaf(w0, x, a0); b0 = fmaf(w0, y, b0);
      a1 = fmaf(w1, x, a1); b1 = fmaf(w1, y, b1);
      a2 = fmaf(w2, x, a2); b2 = fmaf(w2, y, b2);
    }
    *(unsigned int*)(Ub + 2 * tid)       = pack2bf(a0, b0);
    *(unsigned int*)(Ub + 300 + 2 * tid) = pack2bf(a1, b1);
    *(unsigned int*)(Ub + 600 + 2 * tid) = pack2bf(a2, b2);
  } else if (tid < 164) {
    *(unsigned int*)(Ub + 900 + 2 * (tid - 150)) = 0u;   // zero pad 900..927
  }
}

// ---------------------------------------------------------------------------
extern "C" void kernel_launch(void* const* d_in, const int* in_sizes, int n_in,
                              void* d_out, int out_size, void* d_ws, size_t ws_size,
                              hipStream_t stream) {
  const int*   tok    = (const int*)d_in[0];
  const float* emb    = (const float*)d_in[1];
  const float* conv_w = (const float*)d_in[2];
  const float* conv_b = (const float*)d_in[3];
  const float* v      = (const float*)d_in[4];
  const float* vb     = (const float*)d_in[5];
  const float* q      = (const float*)d_in[6];
  float* out = (float*)d_out;

  // Workspace layout (byte offsets). Total ~87.8 MB.
  char* wb = (char*)d_ws;
  float* bias2           = (float*)(wb + 0);          // 200 f32
  float* rinv            = (float*)(wb + 4096);       // 30 f32
  float* part            = (float*)(wb + 8192);       // 30*128 f32 -> 23552
  float* q2s             = (float*)(wb + 23552);      // 200 f32
  float* qsum            = (float*)(wb + 24448);      // 1 f32
  float* Salpha          = (float*)(wb + 24576);      // 32768 f32 -> 155648
  float* expa            = (float*)(wb + 155648);     // 32768*32 f32 -> 4349952
  float* Mt              = (float*)(wb + 4349952);    // 180000 f32 -> 5069952
  unsigned short* embb   = (unsigned short*)(wb + 5070848);   // 20.48MB -> 25550848
  unsigned short* MtT    = (unsigned short*)(wb + 25550848);  // 409600 -> 25960448
  unsigned short* WcT    = (unsigned short*)(wb + 25960448);  // 950272 -> 26910720
  unsigned short* big    = (unsigned short*)(wb + 26910720);  // E3 (41MB) / U (60.8MB)
  unsigned short* E3 = big;
  unsigned short* U  = big;   // E3 dead after scores_kernel

  // 1. Prep
  hipLaunchKernelGGL(prep_Mt_bias, dim3(902), dim3(200), 0, stream,
                     conv_w, conv_b, v, vb, q, Mt, bias2, q2s, qsum);
  hipLaunchKernelGGL(conv_MtT, dim3(E3_LD), dim3(EMB_LD), 0, stream, Mt, MtT);
  hipLaunchKernelGGL(prep_WcT, dim3(WCT_ROWS), dim3(256), 0, stream, conv_w, WcT);
  hipLaunchKernelGGL(prep_emb_bf16, dim3((VOCAB * EMB_LD) / 256), dim3(256), 0, stream,
                     emb, embb);
  hipLaunchKernelGGL(zero_zrow, dim3(3), dim3(256), 0, stream, E3 + (size_t)ZROW * E3_LD);
  // 2. E3[32000,640]bf16 = embb @ MtT^T (holds 2s), bias2 folded into cols [200,400)
  hipLaunchKernelGGL((gemm_mfma<true>), dim3(E3_LD / 128, VOCAB / 128), dim3(256), 0, stream,
                     embb, EMB_LD, MtT, EMB_LD, (void*)E3, E3_LD, E3_LD, EMB_LD,
                     (const float*)nullptr, (const float*)nullptr, bias2);
  // 3. exp(scores) -> expa[b][n]
  hipLaunchKernelGGL(scores_kernel, dim3(BT / 4), dim3(256), 0, stream,
                     tok, E3, q2s, qsum, expa);
  // 4. Softmax denominators (2-stage, deterministic)
  hipLaunchKernelGGL(softmax_part, dim3(128), dim3(256), 0, stream, expa, part);
  hipLaunchKernelGGL(softmax_fin, dim3(NW), dim3(64), 0, stream, part, rinv);
  // 5. U[32768,928]bf16 + Salpha
  hipLaunchKernelGGL(build_U, dim3(BT), dim3(192), 0, stream,
                     tok, embb, expa, rinv, U, Salpha);
  // 6. out[32768,400]f32 = U @ WcT^T + Salpha ⊗ conv_b
  hipLaunchKernelGGL((gemm_mfma<false>), dim3(WCT_ROWS / 128, BT / 128), dim3(256), 0, stream,
                     U, U_LD, WcT, U_LD, (void*)out, CH, CH, U_LD,
                     Salpha, conv_b, (const float*)nullptr);
}